// Round 7
// baseline (268.270 us; speedup 1.0000x reference)
//
#include <hip/hip_runtime.h>

// TPLoss: pred [B,N] fp32, labels [B,N] int32 (0/1) -> scalar fp32
//   s = sigmoid(pred); TP = sum(s*l); SP = sum(s); SL = sum(l)
//   denom = 1 - N + SP + SL - 2*TP ;  loss = -mean_b(TP/denom)
//
// Path model from R1-R6:
//   regular (L1-allocating) reads: 2.65 TB/s cap (per-CU fill queue) [R1-R4]
//   nontemporal (L1-bypass) reads: 3.70 TB/s cap, occupancy-invariant [R5-R6]
//   fabric/HBM proven to 6.9 TB/s by harness fill kernel.
// R7 experiment: drive BOTH paths at once — pred via nt, labels via regular —
// 8+8 loads batched per wave so each CU keeps both queues fed. If the caps
// are independent queues they add: bound = max(134/3.7, 134/2.65) ~= 51 us.

typedef float f4v __attribute__((ext_vector_type(4)));
typedef int   i4v __attribute__((ext_vector_type(4)));

#define BDIM 256
#define WPB 4              // waves per block, one row each
#define ROWS 4096
#define COLS 8192
#define BATCH 8
#define NB 4               // 4 iterations x 8 float4 = 32 chunks = full row

__global__ __launch_bounds__(BDIM) void tploss_rows(
    const float* __restrict__ pred,
    const int* __restrict__ labels,
    float* __restrict__ row_out)
{
    const int lane = threadIdx.x & 63;
    const int row  = blockIdx.x * WPB + (threadIdx.x >> 6);

    const f4v* pb = (const f4v*)(pred   + (size_t)row * COLS) + lane;
    const i4v* lb = (const i4v*)(labels + (size_t)row * COLS) + lane;

    float sp = 0.0f;   // sum sigmoid
    float tp = 0.0f;   // sum sigmoid*label
    int   sl = 0;      // sum label (exact)

    for (int b = 0; b < NB; ++b) {
        const f4v* ph = pb + b * BATCH * 64;
        const i4v* lh = lb + b * BATCH * 64;

        // ---- issue BOTH streams' batches back-to-back: 8 nt (pred) + 8
        // regular (labels) outstanding per wave, feeding the two independent
        // memory queues concurrently ----
        f4v s[BATCH];
        i4v q[BATCH];
#pragma unroll
        for (int i = 0; i < BATCH; ++i) s[i] = __builtin_nontemporal_load(&ph[i * 64]);
#pragma unroll
        for (int i = 0; i < BATCH; ++i) q[i] = lh[i * 64];
#pragma unroll
        for (int i = 0; i < BATCH; ++i) asm volatile("" : "+v"(s[i]));  // pin: defeat load sinking
#pragma unroll
        for (int i = 0; i < BATCH; ++i) asm volatile("" : "+v"(q[i]));

#pragma unroll
        for (int i = 0; i < BATCH; ++i) {
            f4v v = s[i];
            f4v r;
            // sigmoid via v_exp + v_rcp (~2^-21 rel err; rcp(inf)=0 correct limit)
            r.x = __builtin_amdgcn_rcpf(1.0f + __expf(-v.x));
            r.y = __builtin_amdgcn_rcpf(1.0f + __expf(-v.y));
            r.z = __builtin_amdgcn_rcpf(1.0f + __expf(-v.z));
            r.w = __builtin_amdgcn_rcpf(1.0f + __expf(-v.w));
            sp += (r.x + r.y) + (r.z + r.w);
            tp = fmaf(r.x, (float)q[i].x, tp);
            tp = fmaf(r.y, (float)q[i].y, tp);
            tp = fmaf(r.z, (float)q[i].z, tp);
            tp = fmaf(r.w, (float)q[i].w, tp);
            sl += (q[i].x + q[i].y) + (q[i].z + q[i].w);
        }
    }

    float slf = (float)sl;

    // wave-64 butterfly; no LDS, no __syncthreads
#pragma unroll
    for (int off = 32; off > 0; off >>= 1) {
        sp  += __shfl_down(sp,  off, 64);
        tp  += __shfl_down(tp,  off, 64);
        slf += __shfl_down(slf, off, 64);
    }

    if (lane == 0) {
        float denom = 1.0f - (float)COLS + sp + slf - 2.0f * tp;
        row_out[row] = tp / denom;   // one plain store per row, no atomics
    }
}

__global__ __launch_bounds__(BDIM) void tploss_reduce(
    const float* __restrict__ row_out,
    float* __restrict__ out)
{
    const int tid = threadIdx.x;
    float s = 0.0f;
#pragma unroll
    for (int i = 0; i < ROWS / BDIM; ++i)
        s += row_out[i * BDIM + tid];

#pragma unroll
    for (int off = 32; off > 0; off >>= 1)
        s += __shfl_down(s, off, 64);

    __shared__ float sw[BDIM / 64];
    const int wave = tid >> 6;
    const int lane = tid & 63;
    if (lane == 0) sw[wave] = s;
    __syncthreads();

    if (tid == 0) {
        float tot = (sw[0] + sw[1]) + (sw[2] + sw[3]);
        out[0] = -tot * (1.0f / (float)ROWS);
    }
}

extern "C" void kernel_launch(void* const* d_in, const int* in_sizes, int n_in,
                              void* d_out, int out_size, void* d_ws, size_t ws_size,
                              hipStream_t stream) {
    const float* pred   = (const float*)d_in[0];
    const int*   labels = (const int*)d_in[1];
    float* row_out = (float*)d_ws;   // 4096 floats; fully overwritten each call

    tploss_rows<<<ROWS / WPB, BDIM, 0, stream>>>(pred, labels, row_out);
    tploss_reduce<<<1, BDIM, 0, stream>>>(row_out, (float*)d_out);
}